// Round 11
// baseline (105.442 us; speedup 1.0000x reference)
//
#include <hip/hip_runtime.h>
#include <hip/hip_bf16.h>

// NormPool2d: 3x3 reflect-padded window, output = mean - unbiased std.
// x: (16, 96, 224, 224) fp32 -> out same shape, fp32.
//
// Round 11: R10 (global_load_lds double-buffer, 16-row chunks) hit 103.9us
// = 6.30 TB/s DELIVERED bytes (654 MB incl. +12.5% staging overlap) --
// exactly the measured mixed-stream ceiling. Last lever is traffic:
// 56-output-row chunks (58 staged) cut overlap to +3.6% (627 MB, floor
// ~99.5us). One-shot block shape: 6144 blocks (1536 planes x 4 chunks),
// each stages 58 rows (51968 B LDS) via global_load_lds, one
// __syncthreads, computes 56 rows, exits. 3 blocks/CU co-resident: a
// block's stage drain hides under its CU-mates' compute phases.
// Stage/compute math identical to R10's proven code.

#define NP_W 224
#define NP_H 224
#define NP_PLSZ (NP_H * NP_W)
#define NP_ROWB 896                   // bytes per row
#define NP_CH_OUT 56                  // output rows per chunk
#define NP_CH_IN 58                   // staged rows per chunk
#define NP_BYTES (NP_CH_IN * NP_ROWB) // 51968
#define NP_LDS_PAD 53248              // 13 * 4096 (stage overshoot pad)

typedef float f32x4 __attribute__((ext_vector_type(4)));

__device__ __forceinline__ float fin(float s, float q) {
    float mean = s * (1.f / 9.f);
    float var = (q - s * mean) * 0.125f;  // unbiased: (ss - s^2/9)/8
    return mean - __builtin_amdgcn_sqrtf(fmaxf(var, 0.f));
}

__global__ __launch_bounds__(256) void NormPool2d_kernel(
    const float* __restrict__ x, float* __restrict__ out) {
    __shared__ alignas(16) char smem[NP_LDS_PAD];
    const int tid = (int)threadIdx.x;
    const int lane = tid & 63;
    const int wave = tid >> 6;
    const int sl = (lane < 56) ? lane : 55;  // clamp dup lanes
    const bool act = (lane < 56);

    const int plane = blockIdx.x >> 2;
    const int chunk = blockIdx.x & 3;
    const int h0 = chunk * NP_CH_OUT;

    // ---- stage rows h0-1 .. h0+56 (reflect-clamped) into LDS ----
    {
        const char* xplane = (const char*)(x + (size_t)plane * NP_PLSZ);
        #pragma unroll
        for (int j = 0; j < 13; ++j) {
            int off = j * 4096 + tid * 16;       // byte offset in buffer
            int offc = (off > NP_BYTES - 16) ? NP_BYTES - 16 : off;  // pad clamp
            int r0 = offc / NP_ROWB;             // staged row 0..57
            int col = offc - r0 * NP_ROWB;
            int g = h0 - 1 + r0;                 // global row
            g = (g < 0) ? 1 : g;                 // reflect top: -1 -> 1
            g = (g > NP_H - 1) ? NP_H - 2 : g;   // reflect bottom: 224 -> 222
            const float* src = (const float*)(xplane + (size_t)g * NP_ROWB + col);
            float* dst = (float*)(smem + j * 4096 + wave * 1024);
            __builtin_amdgcn_global_load_lds(src, dst, 16, 0, 0);
        }
    }
    __syncthreads();

    // ---- compute 56 output rows; wave handles rows wave*14 + q ----
    {
        float* oplane = out + (size_t)plane * NP_PLSZ;
        #pragma unroll
        for (int q = 0; q < 14; ++q) {
            int k = wave * 14 + q;               // output row within chunk
            const char* base = smem + (size_t)k * NP_ROWB + sl * 16;
            f32x4 a0 = *(const f32x4*)(base);                // row h-1
            f32x4 a1 = *(const f32x4*)(base + NP_ROWB);      // row h
            f32x4 a2 = *(const f32x4*)(base + 2 * NP_ROWB);  // row h+1
            f32x4 sv = a0 + a1 + a2;
            f32x4 sq = a0 * a0 + a1 * a1 + a2 * a2;
            float lf_s = __shfl_up(sv.w, 1);
            float lf_q = __shfl_up(sq.w, 1);
            float rt_s = __shfl_down(sv.x, 1);
            float rt_q = __shfl_down(sq.x, 1);
            if (sl == 0)  { lf_s = sv.y; lf_q = sq.y; }  // reflect w=-1 -> 1
            if (sl == 55) { rt_s = sv.z; rt_q = sq.z; }  // reflect w=W -> W-2
            f32x4 o;
            o.x = fin(lf_s + sv.x + sv.y, lf_q + sq.x + sq.y);
            o.y = fin(sv.x + sv.y + sv.z, sq.x + sq.y + sq.z);
            o.z = fin(sv.y + sv.z + sv.w, sq.y + sq.z + sq.w);
            o.w = fin(sv.z + sv.w + rt_s, sq.z + sq.w + rt_q);
            if (act) {
                f32x4* dst = (f32x4*)(oplane + (size_t)(h0 + k) * NP_W + sl * 4);
                __builtin_nontemporal_store(o, dst);
            }
        }
    }
}

extern "C" void kernel_launch(void* const* d_in, const int* in_sizes, int n_in,
                              void* d_out, int out_size, void* d_ws, size_t ws_size,
                              hipStream_t stream) {
    const float* x = (const float*)d_in[0];
    float* out = (float*)d_out;
    (void)in_sizes; (void)n_in; (void)out_size; (void)d_ws; (void)ws_size;

    NormPool2d_kernel<<<6144, 256, 0, stream>>>(x, out);
}

// Round 12
// 104.083 us; speedup vs baseline: 1.0131x; 1.0131x over previous
//
#include <hip/hip_runtime.h>
#include <hip/hip_bf16.h>

// NormPool2d: 3x3 reflect-padded window, output = mean - unbiased std.
// x: (16, 96, 224, 224) fp32 -> out same shape, fp32.
//
// FINAL (= round 10, the session best: 103.9us). Rationale:
//  - Delivered bytes 655 MB (347 read staged + 308 write) / 103.9us =
//    6.30 TB/s = the measured MI355X mixed-stream ceiling (m13: 6.29).
//  - R11 (56-row one-shot chunks, -8.9% read traffic) regressed to 105.4us
//    by trading occupancy (38%->29%) for traffic -> delivered-byte ceiling,
//    not HBM fetch volume, is binding. Zero-overlap floor 97.8us is not
//    reachable without losing more to residency.
// Structure: __builtin_amdgcn_global_load_lds staging (loads land in LDS,
// compiler can't collapse the pipeline, regalloc can't race it),
// double-buffered 16-output-row chunks (18 staged rows, reflect applied at
// stage time), 2x16 KiB LDS, 1024 blocks = 4/CU uniform residency,
// 21 chunks/block. Compute: wave-per-row, lane = float4 strip, horizontal
// neighbor taps via __shfl of vertical column sums (sum/shuffle commute),
// reflect at w-edges coincides with wave edges. 1 ds_read_b128 x3 + 1
// nontemporal global store per output row per lane.

#define NP_W 224
#define NP_H 224
#define NP_PLSZ (NP_H * NP_W)        // floats per plane
#define NP_ROWB 896                  // bytes per row
#define NP_CPP 14                    // chunks per plane (14*16 = 224)
#define NP_CH_OUT 16                 // output rows per chunk
#define NP_CH_IN 18                  // staged rows per chunk
#define NP_BUF 16384                 // padded buffer bytes (4 x 4096)
#define NP_GRID 1024
#define NP_ITERS 21                  // 1536*14 / 1024

typedef float f32x4 __attribute__((ext_vector_type(4)));

__device__ __forceinline__ float fin(float s, float q) {
    float mean = s * (1.f / 9.f);
    float var = (q - s * mean) * 0.125f;  // unbiased: (ss - s^2/9)/8
    return mean - __builtin_amdgcn_sqrtf(fmaxf(var, 0.f));
}

__global__ __launch_bounds__(256) void NormPool2d_kernel(
    const float* __restrict__ x, float* __restrict__ out) {
    __shared__ alignas(16) char smem[2 * NP_BUF];  // 32 KiB
    const int tid = (int)threadIdx.x;
    const int lane = tid & 63;
    const int wave = tid >> 6;
    const int sl = (lane < 56) ? lane : 55;  // clamp dup lanes
    const bool act = (lane < 56);

    // ---- stage chunk cc's 18 input rows into LDS buffer at bufbase ----
    auto stage = [&](int cc, int bufbase) {
        int plane = cc / NP_CPP;
        int sub = cc - plane * NP_CPP;
        int h0 = sub * NP_CH_OUT;
        const char* xplane =
            (const char*)(x + (size_t)plane * NP_PLSZ);
        #pragma unroll
        for (int j = 0; j < 4; ++j) {
            int off = j * 4096 + tid * 16;      // byte offset in buffer
            int r0 = off / NP_ROWB;             // staged row index 0..18
            int col = off - r0 * NP_ROWB;       // byte col within row
            int r = (r0 > NP_CH_IN - 1) ? NP_CH_IN - 1 : r0;  // pad clamp
            int g = h0 - 1 + r;                 // global row of slot r
            g = (g < 0) ? 1 : g;                // reflect top: -1 -> 1
            g = (g > NP_H - 1) ? NP_H - 2 : g;  // reflect bottom: 224 -> 222
            const float* src =
                (const float*)(xplane + (size_t)g * NP_ROWB + col);
            float* dst = (float*)(smem + bufbase + j * 4096 + wave * 1024);
            __builtin_amdgcn_global_load_lds(src, dst, 16, 0, 0);
        }
    };

    // ---- compute chunk cc's 16 output rows from LDS buffer ----
    auto compute = [&](int cc, int bufbase) {
        int plane = cc / NP_CPP;
        int sub = cc - plane * NP_CPP;
        int h0 = sub * NP_CH_OUT;
        float* oplane = out + (size_t)plane * NP_PLSZ;
        #pragma unroll
        for (int q = 0; q < 4; ++q) {
            int lr = wave * 4 + q;              // output row within chunk
            const char* base = smem + bufbase + (size_t)lr * NP_ROWB + sl * 16;
            f32x4 a0 = *(const f32x4*)(base);                // row h-1
            f32x4 a1 = *(const f32x4*)(base + NP_ROWB);      // row h
            f32x4 a2 = *(const f32x4*)(base + 2 * NP_ROWB);  // row h+1
            f32x4 sv = a0 + a1 + a2;
            f32x4 sq = a0 * a0 + a1 * a1 + a2 * a2;
            float lf_s = __shfl_up(sv.w, 1);
            float lf_q = __shfl_up(sq.w, 1);
            float rt_s = __shfl_down(sv.x, 1);
            float rt_q = __shfl_down(sq.x, 1);
            if (sl == 0)  { lf_s = sv.y; lf_q = sq.y; }  // reflect w=-1 -> 1
            if (sl == 55) { rt_s = sv.z; rt_q = sq.z; }  // reflect w=W -> W-2
            f32x4 o;
            o.x = fin(lf_s + sv.x + sv.y, lf_q + sq.x + sq.y);
            o.y = fin(sv.x + sv.y + sv.z, sq.x + sq.y + sq.z);
            o.z = fin(sv.y + sv.z + sv.w, sq.y + sq.z + sq.w);
            o.w = fin(sv.z + sv.w + rt_s, sq.z + sq.w + rt_q);
            if (act) {
                f32x4* dst = (f32x4*)(oplane +
                    (size_t)(h0 + lr) * NP_W + sl * 4);
                __builtin_nontemporal_store(o, dst);
            }
        }
    };

    int c = blockIdx.x;
    stage(c, 0);
    __syncthreads();

    #pragma unroll 1
    for (int i = 0; i < NP_ITERS; ++i) {
        int cur = (i & 1) * NP_BUF;
        if (i < NP_ITERS - 1) stage(c + NP_GRID, cur ^ NP_BUF);
        __builtin_amdgcn_sched_barrier(0);  // keep stage issued before compute
        compute(c, cur);
        __syncthreads();  // drains vmcnt -> next buffer ready; reads done
        c += NP_GRID;
    }
}

extern "C" void kernel_launch(void* const* d_in, const int* in_sizes, int n_in,
                              void* d_out, int out_size, void* d_ws, size_t ws_size,
                              hipStream_t stream) {
    const float* x = (const float*)d_in[0];
    float* out = (float*)d_out;
    (void)in_sizes; (void)n_in; (void)out_size; (void)d_ws; (void)ws_size;

    NormPool2d_kernel<<<NP_GRID, 256, 0, stream>>>(x, out);
}